// Round 2
// baseline (848.792 us; speedup 1.0000x reference)
//
#include <hip/hip_runtime.h>
#include <math.h>

#define PI_F 3.14159265358979323846f

__device__ __forceinline__ float gelu_exact(float v) {
    return 0.5f * v * (1.0f + erff(v * 0.70710678118654752f));
}
__device__ __forceinline__ int rfl(int x) { return __builtin_amdgcn_readfirstlane(x); }

// ---------------- emb kernel: embk[b*32+c] = t_emb + c_emb + lift_b ----------------
__global__ void k_emb(const float* __restrict__ time_i, const float* __restrict__ conditions,
                      const float* __restrict__ t_embed_w, const float* __restrict__ t_embed_b,
                      const float* __restrict__ c_embed_w, const float* __restrict__ c_embed_b,
                      const float* __restrict__ lift_b, float* __restrict__ embk) {
    int b = blockIdx.x;
    int c = threadIdx.x;   // 0..31
    float acc = t_embed_b[c] + c_embed_b[c] + lift_b[c];
    float tv = time_i[b];
    {
        float ang = PI_F * tv;
        const float* tw = t_embed_w + c * 11;
        for (int i = 0; i < 5; i++) {
            float s, co; sincosf(ang, &s, &co);
            acc += co * tw[i] + s * tw[5 + i];
            ang *= 2.0f;
        }
        acc += tv * tw[10];
    }
    {
        const float* cw = c_embed_w + c * 352;
        for (int l = 0; l < 32; l++) {
            float v = conditions[b * 32 + l];
            float ang = PI_F * v;
            for (int i = 0; i < 5; i++) {
                float s, co; sincosf(ang, &s, &co);
                acc += co * cw[l * 10 + i] + s * cw[l * 10 + 5 + i];
                ang *= 2.0f;
            }
            acc += v * cw[320 + l];
        }
    }
    embk[b * 32 + c] = acc;
}

// ---------------- transpose bypass weights: wtb[l][i][o] = byp_w[l][o][i] ----------------
__global__ void k_wt(const float* __restrict__ byp_w, float* __restrict__ wtb) {
    int idx = blockIdx.x * 256 + threadIdx.x;  // 0..4095
    int l = idx >> 10, rem = idx & 1023;
    int o = rem >> 5, i = rem & 31;
    wtb[(l << 10) + (i << 5) + o] = byp_w[idx];
}

// ---------------- lift: weights via scalar loads, no LDS ----------------
__global__ void k_lift(const float* __restrict__ state_in, const float* __restrict__ node_pos,
                       const float* __restrict__ lift_w, const float* __restrict__ embk,
                       float* __restrict__ x0) {
    int t = threadIdx.x;
    int g = blockIdx.x * 256 + t;
    int b = rfl(g >> 18);
    int n = g & (262144 - 1);

    float f[37];
    const float4 s4 = *(const float4*)(state_in + ((size_t)b * 262144 + n) * 4);
    f[0] = s4.x; f[1] = s4.y; f[2] = s4.z; f[3] = s4.w;
    const float* pp = node_pos + ((size_t)b * 262144 + n) * 3;
    for (int l = 0; l < 3; l++) {
        float p = pp[l];
        float ang = PI_F * p;
        for (int i = 0; i < 5; i++) {
            float s, co; sincosf(ang, &s, &co);
            f[4 + l * 10 + i] = co;
            f[4 + l * 10 + 5 + i] = s;
            ang *= 2.0f;
        }
        f[34 + l] = p;
    }
    for (int o = 0; o < 32; o++) {
        float acc = embk[b * 32 + o];           // uniform -> s_load
        const float* w = lift_w + o * 37;       // uniform -> s_load
        #pragma unroll
        for (int k = 0; k < 37; k++) acc += w[k] * f[k];
        x0[(((size_t)(b * 32 + o)) << 18) + n] = acc;
    }
}

// ---------------- forward Z + Y DFT per (b,c,nx) slab; twiddles by rotation ----------------
__global__ void k_fzy(const float* __restrict__ xin, float2* __restrict__ a2c) {
    __shared__ float xs[64 * 65];
    __shared__ float a1r[8 * 65], a1i[8 * 65];
    __shared__ float prd[256], pid[256];
    int t = threadIdx.x;
    int bc = blockIdx.x >> 6;
    int nx = blockIdx.x & 63;
    const float* src = xin + (((size_t)bc) << 18) + (nx << 12);
    for (int u = 0; u < 4; u++) {
        int i4 = t + u * 256;           // float4 index 0..1023
        float4 v = ((const float4*)src)[i4];
        int row = i4 >> 4;              // ny
        int col = (i4 & 15) * 4;        // nz
        float* d = xs + row * 65 + col;
        d[0] = v.x; d[1] = v.y; d[2] = v.z; d[3] = v.w;
    }
    __syncthreads();
    // stage 1: z-DFT, thread handles kz in {kzg, kzg+4} for its ny
    {
        int ny = t & 63;
        int kzg = t >> 6;               // 0..3
        float cs1, ss1, cs2, ss2;
        sincosf((float)kzg * (PI_F / 32.0f), &ss1, &cs1);
        sincosf((float)(kzg + 4) * (PI_F / 32.0f), &ss2, &cs2);
        float c1 = 1.f, s1 = 0.f, c2 = 1.f, s2 = 0.f;
        float re1 = 0, im1 = 0, re2 = 0, im2 = 0;
        const float* xr = xs + ny * 65;
        for (int nz = 0; nz < 64; nz++) {
            float v = xr[nz];
            re1 += v * c1; im1 -= v * s1;
            re2 += v * c2; im2 -= v * s2;
            float nc1 = c1 * cs1 - s1 * ss1; s1 = s1 * cs1 + c1 * ss1; c1 = nc1;
            float nc2 = c2 * cs2 - s2 * ss2; s2 = s2 * cs2 + c2 * ss2; c2 = nc2;
        }
        a1r[kzg * 65 + ny] = re1; a1i[kzg * 65 + ny] = im1;
        a1r[(kzg + 4) * 65 + ny] = re2; a1i[(kzg + 4) * 65 + ny] = im2;
    }
    __syncthreads();
    // stage 2: y-DFT partials over ny-quarters
    {
        int kz = t >> 5;                // 0..7
        int ky = (t >> 2) & 7;
        int q  = t & 3;
        float cs, ss; sincosf((float)ky * (PI_F / 32.0f), &ss, &cs);
        float c, s;  sincosf((float)(ky * q * 16) * (PI_F / 32.0f), &s, &c);
        float rr = 0, ri = 0;
        const float* ar = a1r + kz * 65 + q * 16;
        const float* ai = a1i + kz * 65 + q * 16;
        for (int j = 0; j < 16; j++) {
            float xr = ar[j], xi = ai[j];
            rr += xr * c + xi * s;
            ri += xi * c - xr * s;
            float nc = c * cs - s * ss; s = s * cs + c * ss; c = nc;
        }
        prd[t] = rr; pid[t] = ri;
    }
    __syncthreads();
    if (t < 64) {
        int kz = t >> 3, ky = t & 7;
        int base = kz * 32 + ky * 4;
        float rr = prd[base] + prd[base + 1] + prd[base + 2] + prd[base + 3];
        float ri = pid[base] + pid[base + 1] + pid[base + 2] + pid[base + 3];
        a2c[((bc * 8 + kz) * 8 + ky) * 64 + nx] = make_float2(rr, ri);
    }
}

// ---------------- forward X DFT per (b,c,kz): 512 blocks ----------------
__global__ void k_fx(const float2* __restrict__ a2c, float* __restrict__ xftr,
                     float* __restrict__ xfti) {
    __shared__ float lar[8 * 65], lai[8 * 65];
    __shared__ float twc[64], tws[64];
    __shared__ float prd[256], pid[256];
    int t = threadIdx.x;
    int bc = blockIdx.x >> 3;
    int kz = blockIdx.x & 7;
    if (t < 64) { float s, c; sincosf((float)t * (PI_F / 32.0f), &s, &c); twc[t] = c; tws[t] = s; }
    for (int u = 0; u < 2; u++) {
        int idx = t + u * 256;          // ky*64+nx
        float2 v = a2c[(bc * 8 + kz) * 512 + idx];
        lar[(idx >> 6) * 65 + (idx & 63)] = v.x;
        lai[(idx >> 6) * 65 + (idx & 63)] = v.y;
    }
    __syncthreads();
    {
        int ky = t >> 5, kx = (t >> 2) & 7, q = t & 3;
        float rr = 0, ri = 0;
        for (int j = 0; j < 16; j++) {
            int nxx = q * 16 + j;
            float ar = lar[ky * 65 + nxx], ai = lai[ky * 65 + nxx];
            int m = (kx * nxx) & 63;
            float c = twc[m], s = tws[m];
            rr += ar * c + ai * s;
            ri += ai * c - ar * s;
        }
        prd[t] = rr; pid[t] = ri;
    }
    __syncthreads();
    if (t < 64) {
        int ky = t >> 3, kx = t & 7;
        int base = ky * 32 + kx * 4;
        float rr = prd[base] + prd[base + 1] + prd[base + 2] + prd[base + 3];
        float ri = pid[base] + pid[base + 1] + pid[base + 2] + pid[base + 3];
        int o = bc * 512 + kz * 64 + ky * 8 + kx;
        xftr[o] = rr; xfti[o] = ri;
    }
}

// ---------------- mode mix per (b,kx,ky) ----------------
__global__ void k_mix(const float* __restrict__ xftr, const float* __restrict__ xfti,
                      const float* __restrict__ wr, const float* __restrict__ wi,
                      float* __restrict__ yftr, float* __restrict__ yfti) {
    __shared__ float lxr[32 * 8], lxi[32 * 8];
    int t = threadIdx.x;
    int b = blockIdx.x >> 6;
    int kx = (blockIdx.x >> 3) & 7;
    int ky = blockIdx.x & 7;
    {
        int i = t >> 3, kz = t & 7;
        int a = ((b * 32 + i) << 9) + kz * 64 + ky * 8 + kx;
        lxr[t] = xftr[a];
        lxi[t] = xfti[a];
    }
    __syncthreads();
    int o = t >> 3, kz = t & 7;
    float yr = 0.0f, yi = 0.0f;
    for (int i = 0; i < 32; i++) {
        float xr = lxr[i * 8 + kz], xi = lxi[i * 8 + kz];
        int wofs = ((i * 32 + o) << 9) + kx * 64 + ky * 8 + kz;   // w[i][o][kx][ky][kz]
        float wrv = wr[wofs], wiv = wi[wofs];
        yr += xr * wrv - xi * wiv;
        yi += xr * wiv + xi * wrv;
    }
    int a = ((b * 32 + o) << 9) + kz * 64 + ky * 8 + kx;
    yftr[a] = yr;
    yfti[a] = yi;
}

// ---------------- inverse X + Y per (b,o,kz); out b2c[bo][kz][nx][ny] float2 ----------------
__global__ void k_ixy(const float* __restrict__ yftr, const float* __restrict__ yfti,
                      float2* __restrict__ b2c) {
    __shared__ float lyr[64], lyi[64];
    __shared__ float b1r[512], b1i[512];
    __shared__ float twc[64], tws[64];
    int t = threadIdx.x;
    int bo = blockIdx.x >> 3;
    int kz = blockIdx.x & 7;
    if (t < 64) { float s, c; sincosf((float)t * (PI_F / 32.0f), &s, &c); twc[t] = c; tws[t] = s; }
    if (t >= 64 && t < 128) {
        int tt = t - 64;
        lyr[tt] = yftr[(bo << 9) + (kz << 6) + tt];
        lyi[tt] = yfti[(bo << 9) + (kz << 6) + tt];
    }
    __syncthreads();
    for (int p = 0; p < 2; p++) {
        int idx = t + p * 256;          // ky*64 + nx
        int ky = idx >> 6, nxx = idx & 63;
        float rr = 0, ri = 0;
        for (int kx = 0; kx < 8; kx++) {
            float yr = lyr[ky * 8 + kx], yi = lyi[ky * 8 + kx];
            int m = (kx * nxx) & 63;
            float c = twc[m], s = tws[m];
            rr += yr * c - yi * s;
            ri += yr * s + yi * c;
        }
        b1r[idx] = rr; b1i[idx] = ri;
    }
    __syncthreads();
    int ny = t & 63;
    int nx0 = t >> 6;                   // 0..3
    float c8[8], s8[8];
    {
        float cs, ss; sincosf((float)ny * (PI_F / 32.0f), &ss, &cs);
        c8[0] = 1.f; s8[0] = 0.f;
        for (int ky = 1; ky < 8; ky++) {
            c8[ky] = c8[ky - 1] * cs - s8[ky - 1] * ss;
            s8[ky] = s8[ky - 1] * cs + c8[ky - 1] * ss;
        }
    }
    size_t obase = ((size_t)bo * 8 + kz) << 12;
    for (int u = 0; u < 4; u++) {
        float rr[4] = {0, 0, 0, 0}, ri[4] = {0, 0, 0, 0};
        int nxb = nx0 * 16 + u * 4;
        for (int ky = 0; ky < 8; ky++) {
            const float4 br = *(const float4*)(b1r + ky * 64 + nxb);
            const float4 bi = *(const float4*)(b1i + ky * 64 + nxb);
            float c = c8[ky], s = s8[ky];
            rr[0] += br.x * c - bi.x * s;  ri[0] += br.x * s + bi.x * c;
            rr[1] += br.y * c - bi.y * s;  ri[1] += br.y * s + bi.y * c;
            rr[2] += br.z * c - bi.z * s;  ri[2] += br.z * s + bi.z * c;
            rr[3] += br.w * c - bi.w * s;  ri[3] += br.w * s + bi.w * c;
        }
        #pragma unroll
        for (int v = 0; v < 4; v++)
            b2c[obase + (size_t)(nxb + v) * 64 + ny] = make_float2(rr[v], ri[v]);
    }
}

// ---------------- final: bypass (s_load weights) + inverse Z + gelu; NO LDS ----------------
__global__ __launch_bounds__(256) void k_fin(
        const float* __restrict__ xin, const float2* __restrict__ b2c,
        const float* __restrict__ wt, const float* __restrict__ bb,
        float* __restrict__ xout) {
    int t = threadIdx.x;
    int b = blockIdx.x >> 12;
    int nxy = blockIdx.x & 4095;
    int nz = t & 63;
    int wq = rfl(t >> 6);               // wave id 0..3, forced scalar

    // z twiddles c7[kz] = cos(kz*nz*pi/32), s7 likewise
    float c7[8], s7[8];
    c7[0] = 1.f; s7[0] = 0.f;
    {
        float cs, ss; sincosf((float)nz * (PI_F / 32.0f), &ss, &cs);
        for (int kz = 1; kz < 8; kz++) {
            c7[kz] = c7[kz - 1] * cs - s7[kz - 1] * ss;
            s7[kz] = s7[kz - 1] * cs + c7[kz - 1] * ss;
        }
    }
    float acc[8];
    #pragma unroll
    for (int k = 0; k < 8; k++) acc[k] = bb[wq * 8 + k];       // s_load
    const float* xcol = xin + (((size_t)b * 32) << 18) + (nxy << 6) + nz;
    #pragma unroll 8
    for (int i = 0; i < 32; i++) {
        float xv = xcol[(size_t)i << 18];                      // coalesced, L1-shared
        const float* wrow = wt + i * 32 + wq * 8;              // s_load_dwordx8
        #pragma unroll
        for (int k = 0; k < 8; k++) acc[k] += wrow[k] * xv;
    }
    const float scale = 1.0f / 262144.0f;
    size_t obase = (((size_t)b * 32) << 18) + (nxy << 6) + nz;
    #pragma unroll
    for (int k = 0; k < 8; k++) {
        int o = wq * 8 + k;
        const float2* bp = b2c + ((((size_t)(b * 32 + o)) * 8) << 12) + nxy;
        float sp = bp[0].x;                                    // kz=0 (s_load_dwordx2)
        #pragma unroll
        for (int kz = 1; kz < 8; kz++) {
            float2 bz = bp[(size_t)kz << 12];
            sp += 2.0f * (bz.x * c7[kz] - bz.y * s7[kz]);
        }
        float v = sp * scale + acc[k];
        xout[obase + ((size_t)o << 18)] = gelu_exact(v);
    }
}

// ---------------- projection: weights via scalar loads, no LDS ----------------
__global__ void k_proj(const float* __restrict__ x4, const float* __restrict__ w1,
                       const float* __restrict__ b1, const float* __restrict__ w2,
                       const float* __restrict__ b2, const float* __restrict__ state_in,
                       float* __restrict__ out) {
    int t = threadIdx.x;
    int g = blockIdx.x * 256 + t;
    int b = rfl(g >> 18);
    int n = g & (262144 - 1);
    float xv[32];
    const float* xb = x4 + (((size_t)b * 32) << 18) + n;
    #pragma unroll 8
    for (int i = 0; i < 32; i++) xv[i] = xb[(size_t)i << 18];
    float h[32];
    for (int o = 0; o < 32; o++) {
        float a = b1[o];
        const float* w = w1 + o * 32;
        #pragma unroll
        for (int i = 0; i < 32; i++) a += w[i] * xv[i];
        h[o] = gelu_exact(a);
    }
    size_t base = ((size_t)b * 262144 + n) * 4;
    float4 sv = *(const float4*)(state_in + base);
    float r[4];
    for (int j = 0; j < 4; j++) {
        float a = b2[j];
        const float* w = w2 + j * 32;
        #pragma unroll
        for (int o = 0; o < 32; o++) a += w[o] * h[o];
        r[j] = a;
    }
    *(float4*)(out + base) = make_float4(sv.x + 0.05f * r[0], sv.y + 0.05f * r[1],
                                         sv.z + 0.05f * r[2], sv.w + 0.05f * r[3]);
}

extern "C" void kernel_launch(void* const* d_in, const int* in_sizes, int n_in,
                              void* d_out, int out_size, void* d_ws, size_t ws_size,
                              hipStream_t stream) {
    const float* state_in   = (const float*)d_in[0];
    const float* node_pos   = (const float*)d_in[1];
    const float* time_i     = (const float*)d_in[3];
    const float* conditions = (const float*)d_in[4];
    const float* t_embed_w  = (const float*)d_in[5];
    const float* t_embed_b  = (const float*)d_in[6];
    const float* c_embed_w  = (const float*)d_in[7];
    const float* c_embed_b  = (const float*)d_in[8];
    const float* lift_w     = (const float*)d_in[9];
    const float* lift_b     = (const float*)d_in[10];
    const float* spec_wr    = (const float*)d_in[11];
    const float* spec_wi    = (const float*)d_in[12];
    const float* byp_w      = (const float*)d_in[13];
    const float* byp_b      = (const float*)d_in[14];
    const float* proj1_w    = (const float*)d_in[15];
    const float* proj1_b    = (const float*)d_in[16];
    const float* proj2_w    = (const float*)d_in[17];
    const float* proj2_b    = (const float*)d_in[18];
    float* out = (float*)d_out;
    float* ws  = (float*)d_ws;

    float*  xA   = ws;                         // 16777216
    float*  xB   = ws + 16777216;              // 16777216
    float2* a2c  = (float2*)(ws + 33554432);   // 262144 float2
    float*  xftr = ws + 34078720;              // 32768
    float*  xfti = ws + 34111488;              // 32768
    float*  yftr = ws + 34144256;              // 32768
    float*  yfti = ws + 34177024;              // 32768
    float2* b2c  = (float2*)(ws + 34209792);   // 2097152 float2
    float*  embk = ws + 38404096;              // 64
    float*  wtb  = ws + 38404160;              // 4096

    k_emb<<<2, 32, 0, stream>>>(time_i, conditions, t_embed_w, t_embed_b,
                                c_embed_w, c_embed_b, lift_b, embk);
    k_wt<<<16, 256, 0, stream>>>(byp_w, wtb);
    k_lift<<<2048, 256, 0, stream>>>(state_in, node_pos, lift_w, embk, xA);

    for (int l = 0; l < 4; l++) {
        float* xin  = (l & 1) ? xB : xA;
        float* xout = (l & 1) ? xA : xB;
        k_fzy<<<4096, 256, 0, stream>>>(xin, a2c);
        k_fx<<<512, 256, 0, stream>>>(a2c, xftr, xfti);
        k_mix<<<128, 256, 0, stream>>>(xftr, xfti, spec_wr + (size_t)l * 524288,
                                       spec_wi + (size_t)l * 524288, yftr, yfti);
        k_ixy<<<512, 256, 0, stream>>>(yftr, yfti, b2c);
        k_fin<<<8192, 256, 0, stream>>>(xin, b2c, wtb + l * 1024, byp_b + l * 32, xout);
    }

    k_proj<<<2048, 256, 0, stream>>>(xA, proj1_w, proj1_b, proj2_w, proj2_b, state_in, out);
}

// Round 3
// 834.171 us; speedup vs baseline: 1.0175x; 1.0175x over previous
//
#include <hip/hip_runtime.h>
#include <math.h>

#define PI_F 3.14159265358979323846f

__device__ __forceinline__ float gelu_exact(float v) {
    return 0.5f * v * (1.0f + erff(v * 0.70710678118654752f));
}
__device__ __forceinline__ int rfl(int x) { return __builtin_amdgcn_readfirstlane(x); }

// ---------------- emb: embk[b*32+c] = t_emb + c_emb + lift_b, parallel over l ----------------
__global__ void k_emb(const float* __restrict__ time_i, const float* __restrict__ conditions,
                      const float* __restrict__ t_embed_w, const float* __restrict__ t_embed_b,
                      const float* __restrict__ c_embed_w, const float* __restrict__ c_embed_b,
                      const float* __restrict__ lift_b, float* __restrict__ embk) {
    __shared__ float red[8][32];
    int t = threadIdx.x;
    int b = blockIdx.x;
    int c = t & 31, lg = t >> 5;
    float acc = 0.0f;
    if (lg == 0) {
        acc = t_embed_b[c] + c_embed_b[c] + lift_b[c];
        float tv = time_i[b];
        float ang = PI_F * tv;
        const float* tw = t_embed_w + c * 11;
        for (int i = 0; i < 5; i++) {
            float s, co; sincosf(ang, &s, &co);
            acc += co * tw[i] + s * tw[5 + i];
            ang *= 2.0f;
        }
        acc += tv * tw[10];
    }
    const float* cw = c_embed_w + c * 352;
    for (int j = 0; j < 4; j++) {
        int l = lg * 4 + j;
        float v = conditions[b * 32 + l];
        float ang = PI_F * v;
        for (int i = 0; i < 5; i++) {
            float s, co; sincosf(ang, &s, &co);
            acc += co * cw[l * 10 + i] + s * cw[l * 10 + 5 + i];
            ang *= 2.0f;
        }
        acc += v * cw[320 + l];
    }
    red[lg][c] = acc;
    __syncthreads();
    if (t < 32) {
        float s = 0.0f;
        for (int g = 0; g < 8; g++) s += red[g][t];
        embk[b * 32 + t] = s;
    }
}

// ---------------- transpose bypass weights: wtb[l][i][o] = byp_w[l][o][i] ----------------
__global__ void k_wt(const float* __restrict__ byp_w, float* __restrict__ wtb) {
    int idx = blockIdx.x * 256 + threadIdx.x;  // 0..4095
    int l = idx >> 10, rem = idx & 1023;
    int o = rem >> 5, i = rem & 31;
    wtb[(l << 10) + (i << 5) + o] = byp_w[idx];
}

// ---------------- lift: weights via scalar loads, no LDS ----------------
__global__ void k_lift(const float* __restrict__ state_in, const float* __restrict__ node_pos,
                       const float* __restrict__ lift_w, const float* __restrict__ embk,
                       float* __restrict__ x0) {
    int t = threadIdx.x;
    int g = blockIdx.x * 256 + t;
    int b = rfl(g >> 18);
    int n = g & (262144 - 1);

    float f[37];
    const float4 s4 = *(const float4*)(state_in + ((size_t)b * 262144 + n) * 4);
    f[0] = s4.x; f[1] = s4.y; f[2] = s4.z; f[3] = s4.w;
    const float* pp = node_pos + ((size_t)b * 262144 + n) * 3;
    for (int l = 0; l < 3; l++) {
        float p = pp[l];
        float ang = PI_F * p;
        for (int i = 0; i < 5; i++) {
            float s, co; sincosf(ang, &s, &co);
            f[4 + l * 10 + i] = co;
            f[4 + l * 10 + 5 + i] = s;
            ang *= 2.0f;
        }
        f[34 + l] = p;
    }
    for (int o = 0; o < 32; o++) {
        float acc = embk[b * 32 + o];           // uniform -> s_load
        const float* w = lift_w + o * 37;       // uniform -> s_load
        #pragma unroll
        for (int k = 0; k < 37; k++) acc += w[k] * f[k];
        x0[(((size_t)(b * 32 + o)) << 18) + n] = acc;
    }
}

// ---------------- k_fz: layer-0 forward z-DFT. x -> a1[b][nxy][o*8+kz] (float2) -------------
__global__ __launch_bounds__(256) void k_fz(const float* __restrict__ xin,
                                            float2* __restrict__ a1) {
    __shared__ float xs[32 * 68];
    int t = threadIdx.x;
    int b = blockIdx.x >> 12;
    int nxy = blockIdx.x & 4095;
    const float* xb = xin + (((size_t)b * 32) << 18) + (nxy << 6);
    for (int u = 0; u < 2; u++) {
        int i4 = t + u * 256;                // 0..511 float4 slots
        int ch = i4 >> 4, q = i4 & 15;
        float4 v = *(const float4*)(xb + ((size_t)ch << 18) + q * 4);
        *(float4*)(xs + ch * 68 + q * 4) = v;
    }
    __syncthreads();
    int o = t >> 3, kz = t & 7;
    float cs, ss; sincosf((float)kz * (PI_F / 32.0f), &ss, &cs);
    float c = 1.0f, s = 0.0f;
    float re = 0.0f, im = 0.0f;
    const float* xr = xs + o * 68;
    for (int nz = 0; nz < 64; nz++) {
        float v = xr[nz];
        re += v * c; im -= v * s;
        float nc = c * cs - s * ss; s = s * cs + c * ss; c = nc;
    }
    a1[((size_t)(b * 4096 + nxy)) * 256 + t] = make_float2(re, im);
}

// ---------------- k_fy: forward y-DFT. a1 -> a2c[((bc*8+kz)*8+ky)*64+nx] ----------------
__global__ __launch_bounds__(256) void k_fy(const float2* __restrict__ a1,
                                            float2* __restrict__ a2c) {
    __shared__ float ar[64 * 65], ai[64 * 65];   // [jj][ny], jj = oo*8+kz
    int t = threadIdx.x;
    int bid = blockIdx.x;
    int og = bid & 3;
    int nx = (bid >> 2) & 63;
    int b  = bid >> 8;
    size_t base2 = ((size_t)(b * 4096 + nx * 64)) * 256 + og * 64;
    for (int u = 0; u < 16; u++) {
        int flat = u * 256 + t;              // ny*64 + jj
        int ny = flat >> 6, jj = flat & 63;
        float2 v = a1[base2 + (size_t)ny * 256 + jj];
        ar[jj * 65 + ny] = v.x;
        ai[jj * 65 + ny] = v.y;
    }
    __syncthreads();
    int jj = t >> 2;                         // oo*8+kz
    int kyq = t & 3;
    int oo = jj >> 3, kz = jj & 7;
    int o_full = og * 8 + oo;
    const float* arr = ar + jj * 65;
    const float* aii = ai + jj * 65;
    for (int h = 0; h < 2; h++) {
        int ky = kyq + h * 4;
        float cs, ss; sincosf((float)ky * (PI_F / 32.0f), &ss, &cs);
        float c = 1.0f, s = 0.0f;
        float rr = 0.0f, ri = 0.0f;
        for (int ny = 0; ny < 64; ny++) {
            float xr = arr[ny], xi = aii[ny];
            rr += xr * c + xi * s;
            ri += xi * c - xr * s;
            float nc = c * cs - s * ss; s = s * cs + c * ss; c = nc;
        }
        a2c[((((size_t)(b * 32 + o_full)) * 8 + kz) * 8 + ky) * 64 + nx] = make_float2(rr, ri);
    }
}

// ---------------- forward X DFT per (b,c,kz): 512 blocks ----------------
__global__ void k_fx(const float2* __restrict__ a2c, float* __restrict__ xftr,
                     float* __restrict__ xfti) {
    __shared__ float lar[8 * 65], lai[8 * 65];
    __shared__ float twc[64], tws[64];
    __shared__ float prd[256], pid[256];
    int t = threadIdx.x;
    int bc = blockIdx.x >> 3;
    int kz = blockIdx.x & 7;
    if (t < 64) { float s, c; sincosf((float)t * (PI_F / 32.0f), &s, &c); twc[t] = c; tws[t] = s; }
    for (int u = 0; u < 2; u++) {
        int idx = t + u * 256;          // ky*64+nx
        float2 v = a2c[(bc * 8 + kz) * 512 + idx];
        lar[(idx >> 6) * 65 + (idx & 63)] = v.x;
        lai[(idx >> 6) * 65 + (idx & 63)] = v.y;
    }
    __syncthreads();
    {
        int ky = t >> 5, kx = (t >> 2) & 7, q = t & 3;
        float rr = 0, ri = 0;
        for (int j = 0; j < 16; j++) {
            int nxx = q * 16 + j;
            float ar = lar[ky * 65 + nxx], ai = lai[ky * 65 + nxx];
            int m = (kx * nxx) & 63;
            float c = twc[m], s = tws[m];
            rr += ar * c + ai * s;
            ri += ai * c - ar * s;
        }
        prd[t] = rr; pid[t] = ri;
    }
    __syncthreads();
    if (t < 64) {
        int ky = t >> 3, kx = t & 7;
        int base = ky * 32 + kx * 4;
        float rr = prd[base] + prd[base + 1] + prd[base + 2] + prd[base + 3];
        float ri = pid[base] + pid[base + 1] + pid[base + 2] + pid[base + 3];
        int o = bc * 512 + kz * 64 + ky * 8 + kx;
        xftr[o] = rr; xfti[o] = ri;
    }
}

// ---------------- mode mix per (b,kx,ky) ----------------
__global__ void k_mix(const float* __restrict__ xftr, const float* __restrict__ xfti,
                      const float* __restrict__ wr, const float* __restrict__ wi,
                      float* __restrict__ yftr, float* __restrict__ yfti) {
    __shared__ float lxr[32 * 8], lxi[32 * 8];
    int t = threadIdx.x;
    int b = blockIdx.x >> 6;
    int kx = (blockIdx.x >> 3) & 7;
    int ky = blockIdx.x & 7;
    {
        int i = t >> 3, kz = t & 7;
        int a = ((b * 32 + i) << 9) + kz * 64 + ky * 8 + kx;
        lxr[t] = xftr[a];
        lxi[t] = xfti[a];
    }
    __syncthreads();
    int o = t >> 3, kz = t & 7;
    float yr = 0.0f, yi = 0.0f;
    for (int i = 0; i < 32; i++) {
        float xr = lxr[i * 8 + kz], xi = lxi[i * 8 + kz];
        int wofs = ((i * 32 + o) << 9) + kx * 64 + ky * 8 + kz;   // w[i][o][kx][ky][kz]
        float wrv = wr[wofs], wiv = wi[wofs];
        yr += xr * wrv - xi * wiv;
        yi += xr * wiv + xi * wrv;
    }
    int a = ((b * 32 + o) << 9) + kz * 64 + ky * 8 + kx;
    yftr[a] = yr;
    yfti[a] = yi;
}

// ---------------- inverse X + Y per (b,o,kz); out b2c[bo][kz][nx][ny] float2 ----------------
__global__ void k_ixy(const float* __restrict__ yftr, const float* __restrict__ yfti,
                      float2* __restrict__ b2c) {
    __shared__ float lyr[64], lyi[64];
    __shared__ float b1r[512], b1i[512];
    __shared__ float twc[64], tws[64];
    int t = threadIdx.x;
    int bo = blockIdx.x >> 3;
    int kz = blockIdx.x & 7;
    if (t < 64) { float s, c; sincosf((float)t * (PI_F / 32.0f), &s, &c); twc[t] = c; tws[t] = s; }
    if (t >= 64 && t < 128) {
        int tt = t - 64;
        lyr[tt] = yftr[(bo << 9) + (kz << 6) + tt];
        lyi[tt] = yfti[(bo << 9) + (kz << 6) + tt];
    }
    __syncthreads();
    for (int p = 0; p < 2; p++) {
        int idx = t + p * 256;          // ky*64 + nx
        int ky = idx >> 6, nxx = idx & 63;
        float rr = 0, ri = 0;
        for (int kx = 0; kx < 8; kx++) {
            float yr = lyr[ky * 8 + kx], yi = lyi[ky * 8 + kx];
            int m = (kx * nxx) & 63;
            float c = twc[m], s = tws[m];
            rr += yr * c - yi * s;
            ri += yr * s + yi * c;
        }
        b1r[idx] = rr; b1i[idx] = ri;
    }
    __syncthreads();
    int ny = t & 63;
    int nx0 = t >> 6;                   // 0..3
    float c8[8], s8[8];
    {
        float cs, ss; sincosf((float)ny * (PI_F / 32.0f), &ss, &cs);
        c8[0] = 1.f; s8[0] = 0.f;
        for (int ky = 1; ky < 8; ky++) {
            c8[ky] = c8[ky - 1] * cs - s8[ky - 1] * ss;
            s8[ky] = s8[ky - 1] * cs + c8[ky - 1] * ss;
        }
    }
    size_t obase = ((size_t)bo * 8 + kz) << 12;
    for (int u = 0; u < 4; u++) {
        float rr[4] = {0, 0, 0, 0}, ri[4] = {0, 0, 0, 0};
        int nxb = nx0 * 16 + u * 4;
        for (int ky = 0; ky < 8; ky++) {
            const float4 br = *(const float4*)(b1r + ky * 64 + nxb);
            const float4 bi = *(const float4*)(b1i + ky * 64 + nxb);
            float c = c8[ky], s = s8[ky];
            rr[0] += br.x * c - bi.x * s;  ri[0] += br.x * s + bi.x * c;
            rr[1] += br.y * c - bi.y * s;  ri[1] += br.y * s + bi.y * c;
            rr[2] += br.z * c - bi.z * s;  ri[2] += br.z * s + bi.z * c;
            rr[3] += br.w * c - bi.w * s;  ri[3] += br.w * s + bi.w * c;
        }
        #pragma unroll
        for (int v = 0; v < 4; v++)
            b2c[obase + (size_t)(nxb + v) * 64 + ny] = make_float2(rr[v], ri[v]);
    }
}

// ---------------- k_fin v3: bypass + inverse-z + gelu + fused forward z-DFT ----------------
__global__ __launch_bounds__(256) void k_fin(
        const float* __restrict__ xin, const float2* __restrict__ b2c,
        const float* __restrict__ wt, const float* __restrict__ bb,
        float* __restrict__ xout, float2* __restrict__ a1, int do_z) {
    __shared__ float xs[32 * 64];       // input x  [i][nz]
    __shared__ float ys[32 * 65];       // output   [o][nz], padded
    int t = threadIdx.x;
    int b = blockIdx.x >> 12;
    int nxy = blockIdx.x & 4095;

    // stage x: 512 float4
    const float* xb = xin + (((size_t)b * 32) << 18) + (nxy << 6);
    for (int u = 0; u < 2; u++) {
        int i4 = t + u * 256;
        int ch = i4 >> 4, q = i4 & 15;
        float4 v = *(const float4*)(xb + ((size_t)ch << 18) + q * 4);
        *(float4*)(xs + ch * 64 + q * 4) = v;
    }
    __syncthreads();

    int nz = t & 63;
    int wq = rfl(t >> 6);               // wave id 0..3 -> o range

    // inverse-z twiddles per thread: c7[kz] = cos(kz*nz*pi/32)
    float c7[8], s7[8];
    c7[0] = 1.f; s7[0] = 0.f;
    {
        float cs, ss; sincosf((float)nz * (PI_F / 32.0f), &ss, &cs);
        for (int kz = 1; kz < 8; kz++) {
            c7[kz] = c7[kz - 1] * cs - s7[kz - 1] * ss;
            s7[kz] = s7[kz - 1] * cs + c7[kz - 1] * ss;
        }
    }

    float acc[8];
    #pragma unroll
    for (int k = 0; k < 8; k++) acc[k] = bb[wq * 8 + k];        // s_load
    #pragma unroll 8
    for (int i = 0; i < 32; i++) {
        float xv = xs[i * 64 + nz];                             // conflict-free ds_read
        const float* wrow = wt + i * 32 + wq * 8;               // s_load_dwordx8
        #pragma unroll
        for (int k = 0; k < 8; k++) acc[k] += wrow[k] * xv;
    }

    const float scale = 1.0f / 262144.0f;
    size_t obase = (((size_t)b * 32) << 18) + (nxy << 6) + nz;
    #pragma unroll
    for (int k = 0; k < 8; k++) {
        int o = wq * 8 + k;
        const float2* bp = b2c + ((((size_t)(b * 32 + o)) * 8) << 12) + nxy;
        float sp = bp[0].x;                                     // wave-uniform s_load
        #pragma unroll
        for (int kz = 1; kz < 8; kz++) {
            float2 bz = bp[(size_t)kz << 12];
            sp += 2.0f * (bz.x * c7[kz] - bz.y * s7[kz]);
        }
        float g = gelu_exact(sp * scale + acc[k]);
        xout[obase + ((size_t)o << 18)] = g;
        ys[o * 65 + nz] = g;
    }

    if (do_z) {
        __syncthreads();
        int o = t >> 3, kz = t & 7;
        float cs, ss; sincosf((float)kz * (PI_F / 32.0f), &ss, &cs);
        float c = 1.0f, s = 0.0f;
        float re = 0.0f, im = 0.0f;
        const float* yr = ys + o * 65;
        for (int n2 = 0; n2 < 64; n2++) {
            float v = yr[n2];
            re += v * c; im -= v * s;
            float nc = c * cs - s * ss; s = s * cs + c * ss; c = nc;
        }
        a1[((size_t)(b * 4096 + nxy)) * 256 + t] = make_float2(re, im);
    }
}

// ---------------- projection: weights via scalar loads, no LDS ----------------
__global__ void k_proj(const float* __restrict__ x4, const float* __restrict__ w1,
                       const float* __restrict__ b1, const float* __restrict__ w2,
                       const float* __restrict__ b2, const float* __restrict__ state_in,
                       float* __restrict__ out) {
    int t = threadIdx.x;
    int g = blockIdx.x * 256 + t;
    int b = rfl(g >> 18);
    int n = g & (262144 - 1);
    float xv[32];
    const float* xb = x4 + (((size_t)b * 32) << 18) + n;
    #pragma unroll 8
    for (int i = 0; i < 32; i++) xv[i] = xb[(size_t)i << 18];
    float h[32];
    for (int o = 0; o < 32; o++) {
        float a = b1[o];
        const float* w = w1 + o * 32;
        #pragma unroll
        for (int i = 0; i < 32; i++) a += w[i] * xv[i];
        h[o] = gelu_exact(a);
    }
    size_t base = ((size_t)b * 262144 + n) * 4;
    float4 sv = *(const float4*)(state_in + base);
    float r[4];
    for (int j = 0; j < 4; j++) {
        float a = b2[j];
        const float* w = w2 + j * 32;
        #pragma unroll
        for (int o = 0; o < 32; o++) a += w[o] * h[o];
        r[j] = a;
    }
    *(float4*)(out + base) = make_float4(sv.x + 0.05f * r[0], sv.y + 0.05f * r[1],
                                         sv.z + 0.05f * r[2], sv.w + 0.05f * r[3]);
}

extern "C" void kernel_launch(void* const* d_in, const int* in_sizes, int n_in,
                              void* d_out, int out_size, void* d_ws, size_t ws_size,
                              hipStream_t stream) {
    const float* state_in   = (const float*)d_in[0];
    const float* node_pos   = (const float*)d_in[1];
    const float* time_i     = (const float*)d_in[3];
    const float* conditions = (const float*)d_in[4];
    const float* t_embed_w  = (const float*)d_in[5];
    const float* t_embed_b  = (const float*)d_in[6];
    const float* c_embed_w  = (const float*)d_in[7];
    const float* c_embed_b  = (const float*)d_in[8];
    const float* lift_w     = (const float*)d_in[9];
    const float* lift_b     = (const float*)d_in[10];
    const float* spec_wr    = (const float*)d_in[11];
    const float* spec_wi    = (const float*)d_in[12];
    const float* byp_w      = (const float*)d_in[13];
    const float* byp_b      = (const float*)d_in[14];
    const float* proj1_w    = (const float*)d_in[15];
    const float* proj1_b    = (const float*)d_in[16];
    const float* proj2_w    = (const float*)d_in[17];
    const float* proj2_b    = (const float*)d_in[18];
    float* out = (float*)d_out;
    float* ws  = (float*)d_ws;

    float*  xA   = ws;                         // 16777216 floats
    float*  xB   = ws + 16777216;              // 16777216
    float2* a2c  = (float2*)(ws + 33554432);   // 262144 float2
    float*  xftr = ws + 34078720;              // 32768
    float*  xfti = ws + 34111488;              // 32768
    float*  yftr = ws + 34144256;              // 32768
    float*  yfti = ws + 34177024;              // 32768
    float2* b2c  = (float2*)(ws + 34209792);   // 2097152 float2 -> ends 38404096
    float*  embk = ws + 38404096;              // 64
    float*  wtb  = ws + 38404160;              // 4096 -> ends 38408256
    float2* a1   = (float2*)(ws + 38408256);   // 2097152 float2 -> ends 42602560

    k_emb<<<2, 256, 0, stream>>>(time_i, conditions, t_embed_w, t_embed_b,
                                 c_embed_w, c_embed_b, lift_b, embk);
    k_wt<<<16, 256, 0, stream>>>(byp_w, wtb);
    k_lift<<<2048, 256, 0, stream>>>(state_in, node_pos, lift_w, embk, xA);
    k_fz<<<8192, 256, 0, stream>>>(xA, a1);

    for (int l = 0; l < 4; l++) {
        float* xin  = (l & 1) ? xB : xA;
        float* xout = (l & 1) ? xA : xB;
        k_fy<<<512, 256, 0, stream>>>(a1, a2c);
        k_fx<<<512, 256, 0, stream>>>(a2c, xftr, xfti);
        k_mix<<<128, 256, 0, stream>>>(xftr, xfti, spec_wr + (size_t)l * 524288,
                                       spec_wi + (size_t)l * 524288, yftr, yfti);
        k_ixy<<<512, 256, 0, stream>>>(yftr, yfti, b2c);
        k_fin<<<8192, 256, 0, stream>>>(xin, b2c, wtb + l * 1024, byp_b + l * 32,
                                        xout, a1, (l < 3) ? 1 : 0);
    }

    k_proj<<<2048, 256, 0, stream>>>(xA, proj1_w, proj1_b, proj2_w, proj2_b, state_in, out);
}